// Round 12
// baseline (47.545 us; speedup 1.0000x reference)
//
#include <hip/hip_runtime.h>
#include <cfloat>
#include <math.h>

#define NB   16
#define NGT  60
#define NA   8400
#define KNN  10
#define NCAND (NGT*KNN)   // 600
#define EPSF 1e-7f
#define PIF  3.14159265358979f

#define FOCAL_BLOCKS  2100   // 2,688,000 / (2100*256) = exactly 5 vec4s/thread
#define SPARSE_BLOCKS 240    // 960 (img,gt) pairs, 4 waves/block
#define K1_BLOCKS (FOCAL_BLOCKS + SPARSE_BLOCKS)

// vec4 index space over (p0,p1,p2) concatenated: 2,822,400 vec4s total.
// multiples of 21 are row starts (box channels, skipped); rest -> focal.
#define NV0   2150400u
#define NV1    537600u
#define NV2    134400u
#define FOCAL_COUNT 2688000u  // 20/21 of total

#define LOG2E 1.44269504088896341f
#define LN2   0.69314718055994531f

__device__ __forceinline__ float fexp2(float x){ return __builtin_amdgcn_exp2f(x); }
__device__ __forceinline__ float flog2(float x){ return __builtin_amdgcn_logf(x); }
__device__ __forceinline__ float frcp (float x){ return __builtin_amdgcn_rcpf(x); }

__device__ __forceinline__ float fsigm(float x){
  return frcp(1.0f + fexp2(-x*LOG2E));
}
__device__ __forceinline__ float fsoftplus(float x){
  float u = fexp2(-fabsf(x)*LOG2E);
  return fmaxf(x,0.f) + LN2*flog2(1.0f + u);
}
// fbg = softplus(x)*sigmoid(x)^2 = (x + ln(1+u)) / (1+u)^2,  u = e^-x
__device__ __forceinline__ float fbg(float x){
  float u = fexp2(fminf(-x*LOG2E, 126.0f));
  float t = frcp(1.0f + u);
  return (x + LN2*flog2(1.0f + u)) * t * t;
}

// one focal element group: remap u -> class vec4, load, 4x fbg
__device__ __forceinline__ float focal_fbg4(const float* __restrict__ p0,
                                            const float* __restrict__ p1,
                                            const float* __restrict__ p2, unsigned u){
  unsigned g = u / 20u;
  unsigned v = 21u*g + (u - 20u*g) + 1u;   // never a multiple of 21
  const float* p; unsigned vloc;
  if (v < NV0)          { p=p0; vloc = v; }
  else if (v < NV0+NV1) { p=p1; vloc = v - NV0; }
  else                  { p=p2; vloc = v - (NV0+NV1); }
  float4 x4 = *(const float4*)(p + (size_t)vloc*4u);
  return fbg(x4.x) + fbg(x4.y) + fbg(x4.z) + fbg(x4.w);
}

// row pointer + grid coords for an anchor id (decode-on-demand)
struct ARow { const float* q; float stf; int i, j; };
__device__ __forceinline__ ARow anchor_row(const float* p0,const float* p1,const float* p2,int img,int a){
  ARow r;
  if (a < 6400){ int l=a;      r.q = p0 + (size_t)(img*6400 + l)*84; r.stf= 8.f; r.i=l/80; r.j=l-80*r.i; }
  else if (a < 8000){ int l=a-6400; r.q = p1 + (size_t)(img*1600 + l)*84; r.stf=16.f; r.i=l/40; r.j=l-40*r.i; }
  else { int l=a-8000;         r.q = p2 + (size_t)(img*400  + l)*84; r.stf=32.f; r.i=l/20; r.j=l-20*r.i; }
  return r;
}
__device__ __forceinline__ float4 decode_box_xywh(const ARow& r){
  float4 x4 = *(const float4*)r.q;
  float px = (fsigm(x4.x)*2.f - 0.5f + (float)r.j)*r.stf;
  float py = (fsigm(x4.y)*2.f - 0.5f + (float)r.i)*r.stf;
  float pw = fsoftplus(x4.z)*r.stf;
  float ph = fsoftplus(x4.w)*r.stf;
  return make_float4(px,py,pw,ph);
}

// K1: blocks [0,2100) = background focal stream; blocks [2100,2340) = sparse
// path, one wave per (img,gt): exact windowed top-10 + scatter-match.
// Window-prune proof: the 16 L0 anchors in the 4x4 cell block around the GT
// center have dist^2 <= 28^2+28^2 = 1568 => d10 <= 1568; any anchor outside
// the 13x13/7x7/5x5 windows has min-possible dist^2 > 1568 (strict).
// Scatter-match: this wave evaluates ITS 10 candidates vs all 60 GTs and
// writes per-(img,g,j) packed (cost_bits<<32)|slot; slot = g*10+r is the
// reference's flattened cand index, so uint64-min == argmin w/ first-
// occurrence tie-break. Union over g == full 600x60 cost matrix.
__global__ __launch_bounds__(256) void k1_kernel(const float* __restrict__ p0,
                                                 const float* __restrict__ p1,
                                                 const float* __restrict__ p2,
                                                 const float* __restrict__ gt,
                                                 const int* __restrict__ labels,
                                                 int* __restrict__ cand,
                                                 unsigned long long* __restrict__ partials,
                                                 float* __restrict__ fsum){
  if (blockIdx.x < FOCAL_BLOCKS){
    // ---- focal blocks ----
    __shared__ float sbuf[4];
    const unsigned S = FOCAL_BLOCKS*256u;   // 537600
    unsigned u = blockIdx.x*256u + threadIdx.x;
    float s0 = focal_fbg4(p0,p1,p2, u);
    float s1 = focal_fbg4(p0,p1,p2, u +   S);
    float s2 = focal_fbg4(p0,p1,p2, u + 2*S);
    float s3 = focal_fbg4(p0,p1,p2, u + 3*S);
    float s4 = focal_fbg4(p0,p1,p2, u + 4*S);
    float sum = (((s0 + s1) + (s2 + s3)) + s4) * 0.75f;
    #pragma unroll
    for (int off=32; off>0; off>>=1) sum += __shfl_xor(sum, off);
    int wid = threadIdx.x >> 6;
    if ((threadIdx.x & 63) == 0) sbuf[wid] = sum;
    __syncthreads();
    if (threadIdx.x == 0) fsum[blockIdx.x] = sbuf[0]+sbuf[1]+sbuf[2]+sbuf[3];
    return;
  }

  // ---- sparse blocks: one wave per (img,gt) pair ----
  int wid  = threadIdx.x >> 6;
  int lane = threadIdx.x & 63;
  int pair = (blockIdx.x - FOCAL_BLOCKS)*4 + wid;   // 0..959
  int img = pair / NGT, g = pair - img*NGT;
  const float* gb = gt + (size_t)(img*NGT + g)*4;
  float tcx = (gb[0]+gb[2])*0.5f, tcy = (gb[1]+gb[3])*0.5f;

  int jx0 = (int)(tcx * 0.125f),   iy0 = (int)(tcy * 0.125f);
  int jx1 = (int)(tcx * 0.0625f),  iy1 = (int)(tcy * 0.0625f);
  int jx2 = (int)(tcx * 0.03125f), iy2 = (int)(tcy * 0.03125f);

  float d0=FLT_MAX,d1=FLT_MAX,d2=FLT_MAX,d3=FLT_MAX;
  int   a0,a1,a2,a3;
  #pragma unroll
  for (int s=0; s<4; s++){
    int c = lane + 64*s;
    float dd = FLT_MAX; int aa = 9000000 + c;
    const float* p; int i, j, S, base, rowmul, valid = 1; float stf;
    if (c < 169)      { int r=c/13,  q=c-13*r;           i=iy0-6+r; j=jx0-6+q; S=80; base=0;    p=p0; rowmul=6400; stf= 8.f; }
    else if (c < 218) { int t=c-169; int r=t/7, q=t-7*r; i=iy1-3+r; j=jx1-3+q; S=40; base=6400; p=p1; rowmul=1600; stf=16.f; }
    else if (c < 243) { int t=c-218; int r=t/5, q=t-5*r; i=iy2-2+r; j=jx2-2+q; S=20; base=8000; p=p2; rowmul=400;  stf=32.f; }
    else { valid = 0; i=j=0; S=1; base=0; p=p0; rowmul=0; stf=0.f; }
    if (valid && i>=0 && i<S && j>=0 && j<S){
      int local = i*S + j;
      const float* q4 = p + (size_t)(img*rowmul + local)*84u;
      float2 xy = *(const float2*)q4;
      float px = (fsigm(xy.x)*2.f - 0.5f + (float)j)*stf;
      float py = (fsigm(xy.y)*2.f - 0.5f + (float)i)*stf;
      float dx=px-tcx, dy=py-tcy;
      dd = dx*dx + dy*dy;
      aa = base + local;
    }
    if (s==0){ d0=dd; a0=aa; } else if (s==1){ d1=dd; a1=aa; }
    else if (s==2){ d2=dd; a2=aa; } else { d3=dd; a3=aa; }
  }

  int anc_r[KNN];                       // winners, known to ALL lanes (static idx)
  #pragma unroll
  for (int r=0; r<KNN; r++){
    float v = d0; int anc = a0;
    if (d1 < v || (d1==v && a1<anc)){ v=d1; anc=a1; }
    if (d2 < v || (d2==v && a2<anc)){ v=d2; anc=a2; }
    if (d3 < v || (d3==v && a3<anc)){ v=d3; anc=a3; }
    #pragma unroll
    for (int off=32; off>0; off>>=1){
      float v2 = __shfl_xor(v, off);
      int  A2 = __shfl_xor(anc, off);
      if (v2 < v || (v2==v && A2<anc)){ v=v2; anc=A2; }
    }
    if (a0==anc) d0=FLT_MAX;
    if (a1==anc) d1=FLT_MAX;
    if (a2==anc) d2=FLT_MAX;
    if (a3==anc) d3=FLT_MAX;
    anc_r[r] = anc;
    if (lane == 0) cand[(size_t)pair*KNN + r] = anc;
  }

  // scatter-match: lane j = GT j; eval this wave's 10 candidates
  bool jv = (lane < NGT);
  float4 gbj = make_float4(0.f,0.f,0.f,0.f);
  int labj = 0;
  if (jv){
    gbj  = *(const float4*)(gt + (size_t)(img*NGT + lane)*4);
    labj = labels[img*NGT + lane];
  }
  float a2g = fmaxf(gbj.z-gbj.x,0.f)*fmaxf(gbj.w-gbj.y,0.f);
  unsigned long long best = ~0ull;
  #pragma unroll
  for (int r=0; r<KNN; r++){
    int a = anc_r[r];
    ARow ar = anchor_row(p0,p1,p2,img,a);
    float4 b = decode_box_xywh(ar);     // broadcast row load (same addr all lanes)
    float bx1=b.x-b.z*0.5f, by1=b.y-b.w*0.5f, bx2=b.x+b.z*0.5f, by2=b.y+b.w*0.5f;
    float a1 = fmaxf(bx2-bx1,0.f)*fmaxf(by2-by1,0.f);
    float ix1=fmaxf(bx1,gbj.x), iy1=fmaxf(by1,gbj.y);
    float ix2=fminf(bx2,gbj.z), iy2=fminf(by2,gbj.w);
    float inter = fmaxf(ix2-ix1,0.f)*fmaxf(iy2-iy1,0.f);
    float uni = a1 + a2g - inter + EPSF;
    float iou = fminf(fmaxf(inter/uni,0.f),1.f);
    float lg = ar.q[4+labj];            // per-lane gather within the 336B row
    float cost = 0.5f*(1.f - fsigm(lg)) + 6.f*(1.f - iou);
    unsigned long long pk = ((unsigned long long)__float_as_uint(cost) << 32)
                          | (unsigned)(g*KNN + r);
    if (pk < best) best = pk;           // slot in low bits: exact tie-break
  }
  if (jv) partials[((size_t)img*NGT + g)*NGT + lane] = best;
}

// K2: single block, 16 waves (one image each): reduce partials -> matched,
// ciou + dedup'd corrections + focal partial reduction + final scalar
__global__ __launch_bounds__(1024) void k2_kernel(const unsigned long long* __restrict__ partials,
                                                  const int* __restrict__ cand,
                                                  const float* __restrict__ gt,
                                                  const int* __restrict__ labels,
                                                  const float* __restrict__ p0,
                                                  const float* __restrict__ p1,
                                                  const float* __restrict__ p2,
                                                  const float* __restrict__ fsum,
                                                  float* __restrict__ out){
  int tid = threadIdx.x;
  int wid = tid >> 6;        // image
  int lane = tid & 63;
  __shared__ int sm[NB][NGT];
  __shared__ int sl[NB][NGT];
  __shared__ float wb[NB], wc[NB], wf[NB];
  int img = wid;
  if (lane < NGT){
    unsigned long long best = ~0ull;
    #pragma unroll 4
    for (int g2=0; g2<NGT; g2++){
      unsigned long long v = partials[((size_t)img*NGT + g2)*NGT + lane];
      if (v < best) best = v;
    }
    int slot = (int)(best & 0xffffffffull);
    sm[img][lane] = cand[img*NCAND + slot];
    sl[img][lane] = labels[img*NGT + lane];
  }
  __syncthreads();

  float local_box = 0.f, local_corr = 0.f;
  if (lane < NGT){
    int j = lane;
    int m = sm[img][j];
    ARow ar = anchor_row(p0,p1,p2,img,m);
    float4 pb = decode_box_xywh(ar);
    float px1=pb.x-pb.z*0.5f, py1=pb.y-pb.w*0.5f, px2=pb.x+pb.z*0.5f, py2=pb.y+pb.w*0.5f;
    const float* gb = gt + (size_t)(img*NGT + j)*4;
    float gx=gb[0], gy=gb[1], gz=gb[2], gw=gb[3];
    float pw=fmaxf(px2-px1,EPSF), ph=fmaxf(py2-py1,EPSF);
    float tw=fmaxf(gz-gx,EPSF),  th=fmaxf(gw-gy,EPSF);
    float inter = fmaxf(fminf(px2,gz)-fmaxf(px1,gx),0.f)*fmaxf(fminf(py2,gw)-fmaxf(py1,gy),0.f);
    float uni = pw*ph + tw*th - inter + EPSF;
    float iou = inter/uni;
    float dcx = (px1+px2)*0.5f - (gx+gz)*0.5f;
    float dcy = (py1+py2)*0.5f - (gy+gw)*0.5f;
    float cd = dcx*dcx + dcy*dcy;
    float cw = fmaxf(px2,gz) - fminf(px1,gx);
    float ch = fmaxf(py2,gw) - fminf(py1,gy);
    float c2 = cw*cw + ch*ch + EPSF;
    float dv = atanf(tw/th) - atanf(pw/ph);
    float v  = (4.f/(PIF*PIF))*dv*dv;
    float alpha = v/(v - iou + 1.f + EPSF);
    float ciou = iou - cd/c2 - alpha*v;
    local_box = 1.f - ciou;

    int lab = sl[img][j];
    bool dup = false;
    for (int j2=0; j2<j; j2++)
      if (sm[img][j2]==m && sl[img][j2]==lab){ dup=true; break; }
    if (!dup){
      float x = ar.q[4+lab];
      float s  = fsigm(x);
      float u  = fexp2(-fabsf(x)*LOG2E);
      float lt = LN2*flog2(1.0f + u);
      float sp_pos = fmaxf(-x,0.f) + lt;   // ce for tgt=1
      float sp_neg = fmaxf( x,0.f) + lt;   // ce for tgt=0
      local_corr = 0.25f*sp_pos*(1.f-s)*(1.f-s) - 0.75f*sp_neg*s*s;
    }
  }
  float local_f = fsum[tid] + fsum[tid + 1024];
  if (tid < FOCAL_BLOCKS - 2048) local_f += fsum[tid + 2048];
  #pragma unroll
  for (int off=32; off>0; off>>=1){
    local_box  += __shfl_xor(local_box,  off);
    local_corr += __shfl_xor(local_corr, off);
    local_f    += __shfl_xor(local_f,    off);
  }
  if (lane == 0){ wb[wid]=local_box; wc[wid]=local_corr; wf[wid]=local_f; }
  __syncthreads();
  if (tid == 0){
    float sb=0.f, sc=0.f, sf=0.f;
    #pragma unroll
    for (int k=0;k<NB;k++){ sb+=wb[k]; sc+=wc[k]; sf+=wf[k]; }
    out[0] = (7.5f*sb + 0.5f*(sf + sc)) / (60.f*16.f);
  }
}

extern "C" void kernel_launch(void* const* d_in, const int* in_sizes, int n_in,
                              void* d_out, int out_size, void* d_ws, size_t ws_size,
                              hipStream_t stream){
  const float* p0 = (const float*)d_in[0];
  const float* p1 = (const float*)d_in[1];
  const float* p2 = (const float*)d_in[2];
  const float* gt = (const float*)d_in[3];
  const int* labels = (const int*)d_in[4];
  float* out = (float*)d_out;

  unsigned long long* partials = (unsigned long long*)d_ws;               // 460.8 KB (8-aligned)
  float* fsum = (float*)((char*)d_ws + (size_t)NB*NGT*NGT*8);             // 8.4 KB
  int*   cand = (int*)((char*)fsum + FOCAL_BLOCKS*sizeof(float));         // 38.4 KB

  k1_kernel<<<K1_BLOCKS, 256, 0, stream>>>(p0, p1, p2, gt, labels, cand, partials, fsum);
  k2_kernel<<<1, 1024, 0, stream>>>(partials, cand, gt, labels, p0, p1, p2, fsum, out);
}

// Round 13
// 38.458 us; speedup vs baseline: 1.2363x; 1.2363x over previous
//
#include <hip/hip_runtime.h>
#include <cfloat>
#include <math.h>

#define NB   16
#define NGT  60
#define NA   8400
#define KNN  10
#define NCAND (NGT*KNN)   // 600
#define EPSF 1e-7f
#define PIF  3.14159265358979f

#define SPARSE_BLOCKS 240    // 960 (img,gt) pairs, 4 waves/block, sparse FIRST
#define FOCAL_BLOCKS  2100   // 2,688,000 / (2100*256) = exactly 5 vec4s/thread
#define K1_BLOCKS (SPARSE_BLOCKS + FOCAL_BLOCKS)

// vec4 index space over (p0,p1,p2) concatenated: 2,822,400 vec4s total.
// multiples of 21 are row starts (box channels, skipped); rest -> focal.
#define NV0   2150400u
#define NV1    537600u
#define NV2    134400u
#define FOCAL_COUNT 2688000u  // 20/21 of total

#define LOG2E 1.44269504088896341f
#define LN2   0.69314718055994531f

__device__ __forceinline__ float fexp2(float x){ return __builtin_amdgcn_exp2f(x); }
__device__ __forceinline__ float flog2(float x){ return __builtin_amdgcn_logf(x); }
__device__ __forceinline__ float frcp (float x){ return __builtin_amdgcn_rcpf(x); }

__device__ __forceinline__ float fsigm(float x){
  return frcp(1.0f + fexp2(-x*LOG2E));
}
__device__ __forceinline__ float fsoftplus(float x){
  float u = fexp2(-fabsf(x)*LOG2E);
  return fmaxf(x,0.f) + LN2*flog2(1.0f + u);
}
// fbg = softplus(x)*sigmoid(x)^2 = (x + ln(1+u)) / (1+u)^2,  u = e^-x
__device__ __forceinline__ float fbg(float x){
  float u = fexp2(fminf(-x*LOG2E, 126.0f));
  float t = frcp(1.0f + u);
  return (x + LN2*flog2(1.0f + u)) * t * t;
}

// one focal element group: remap u -> class vec4, load, 4x fbg
__device__ __forceinline__ float focal_fbg4(const float* __restrict__ p0,
                                            const float* __restrict__ p1,
                                            const float* __restrict__ p2, unsigned u){
  unsigned g = u / 20u;
  unsigned v = 21u*g + (u - 20u*g) + 1u;   // never a multiple of 21
  const float* p; unsigned vloc;
  if (v < NV0)          { p=p0; vloc = v; }
  else if (v < NV0+NV1) { p=p1; vloc = v - NV0; }
  else                  { p=p2; vloc = v - (NV0+NV1); }
  float4 x4 = *(const float4*)(p + (size_t)vloc*4u);
  return fbg(x4.x) + fbg(x4.y) + fbg(x4.z) + fbg(x4.w);
}

// row pointer + grid coords for an anchor id (decode-on-demand)
struct ARow { const float* q; float stf; int i, j; };
__device__ __forceinline__ ARow anchor_row(const float* p0,const float* p1,const float* p2,int img,int a){
  ARow r;
  if (a < 6400){ int l=a;      r.q = p0 + (size_t)(img*6400 + l)*84; r.stf= 8.f; r.i=l/80; r.j=l-80*r.i; }
  else if (a < 8000){ int l=a-6400; r.q = p1 + (size_t)(img*1600 + l)*84; r.stf=16.f; r.i=l/40; r.j=l-40*r.i; }
  else { int l=a-8000;         r.q = p2 + (size_t)(img*400  + l)*84; r.stf=32.f; r.i=l/20; r.j=l-20*r.i; }
  return r;
}
__device__ __forceinline__ float4 decode_box_xywh(const ARow& r){
  float4 x4 = *(const float4*)r.q;
  float px = (fsigm(x4.x)*2.f - 0.5f + (float)r.j)*r.stf;
  float py = (fsigm(x4.y)*2.f - 0.5f + (float)r.i)*r.stf;
  float pw = fsoftplus(x4.z)*r.stf;
  float ph = fsoftplus(x4.w)*r.stf;
  return make_float4(px,py,pw,ph);
}

// K1: blocks [0,240) = sparse path (one wave per (img,gt): exact windowed
// top-10 + scatter-match, block-reduced); blocks [240,2340) = focal stream.
// Window-prune proof: the 16 L0 anchors in the 4x4 cell block around the GT
// center have dist^2 <= 28^2+28^2 = 1568 => d10 <= 1568; any anchor outside
// the 13x13/7x7/5x5 windows has min-possible dist^2 > 1568 (strict).
// Scatter-match key: (cost_bits<<32)|(slot<<14)|anchor, slot = g*10+r = the
// reference's flattened cand index (cost>0 so float bits are monotone) ->
// u64-min == argmin with first-occurrence tie-break; anchor rides along.
// Each block min-reduces its 4 GTs' keys per j -> partials[block][j].
__global__ __launch_bounds__(256) void k1_kernel(const float* __restrict__ p0,
                                                 const float* __restrict__ p1,
                                                 const float* __restrict__ p2,
                                                 const float* __restrict__ gt,
                                                 const int* __restrict__ labels,
                                                 unsigned long long* __restrict__ partials,
                                                 float* __restrict__ fsum){
  if (blockIdx.x >= SPARSE_BLOCKS){
    // ---- focal blocks ----
    __shared__ float sbuf[4];
    const unsigned S = FOCAL_BLOCKS*256u;   // 537600
    unsigned u = (blockIdx.x - SPARSE_BLOCKS)*256u + threadIdx.x;
    float s0 = focal_fbg4(p0,p1,p2, u);
    float s1 = focal_fbg4(p0,p1,p2, u +   S);
    float s2 = focal_fbg4(p0,p1,p2, u + 2*S);
    float s3 = focal_fbg4(p0,p1,p2, u + 3*S);
    float s4 = focal_fbg4(p0,p1,p2, u + 4*S);
    float sum = (((s0 + s1) + (s2 + s3)) + s4) * 0.75f;
    #pragma unroll
    for (int off=32; off>0; off>>=1) sum += __shfl_xor(sum, off);
    int wid = threadIdx.x >> 6;
    if ((threadIdx.x & 63) == 0) sbuf[wid] = sum;
    __syncthreads();
    if (threadIdx.x == 0) fsum[blockIdx.x - SPARSE_BLOCKS] = sbuf[0]+sbuf[1]+sbuf[2]+sbuf[3];
    return;
  }

  // ---- sparse blocks: 4 waves = 4 consecutive GTs of ONE image ----
  int wid  = threadIdx.x >> 6;
  int lane = threadIdx.x & 63;
  int pair = blockIdx.x*4 + wid;        // 0..959; img constant per block (60%4==0)
  int img = pair / NGT, g = pair - img*NGT;
  const float* gb = gt + (size_t)(img*NGT + g)*4;
  float tcx = (gb[0]+gb[2])*0.5f, tcy = (gb[1]+gb[3])*0.5f;

  int jx0 = (int)(tcx * 0.125f),   iy0 = (int)(tcy * 0.125f);
  int jx1 = (int)(tcx * 0.0625f),  iy1 = (int)(tcy * 0.0625f);
  int jx2 = (int)(tcx * 0.03125f), iy2 = (int)(tcy * 0.03125f);

  float d0=FLT_MAX,d1=FLT_MAX,d2=FLT_MAX,d3=FLT_MAX;
  int   a0,a1,a2,a3;
  #pragma unroll
  for (int s=0; s<4; s++){
    int c = lane + 64*s;
    float dd = FLT_MAX; int aa = 9000000 + c;
    const float* p; int i, j, S, base, rowmul, valid = 1; float stf;
    if (c < 169)      { int r=c/13,  q=c-13*r;           i=iy0-6+r; j=jx0-6+q; S=80; base=0;    p=p0; rowmul=6400; stf= 8.f; }
    else if (c < 218) { int t=c-169; int r=t/7, q=t-7*r; i=iy1-3+r; j=jx1-3+q; S=40; base=6400; p=p1; rowmul=1600; stf=16.f; }
    else if (c < 243) { int t=c-218; int r=t/5, q=t-5*r; i=iy2-2+r; j=jx2-2+q; S=20; base=8000; p=p2; rowmul=400;  stf=32.f; }
    else { valid = 0; i=j=0; S=1; base=0; p=p0; rowmul=0; stf=0.f; }
    if (valid && i>=0 && i<S && j>=0 && j<S){
      int local = i*S + j;
      const float* q4 = p + (size_t)(img*rowmul + local)*84u;
      float2 xy = *(const float2*)q4;
      float px = (fsigm(xy.x)*2.f - 0.5f + (float)j)*stf;
      float py = (fsigm(xy.y)*2.f - 0.5f + (float)i)*stf;
      float dx=px-tcx, dy=py-tcy;
      dd = dx*dx + dy*dy;
      aa = base + local;
    }
    if (s==0){ d0=dd; a0=aa; } else if (s==1){ d1=dd; a1=aa; }
    else if (s==2){ d2=dd; a2=aa; } else { d3=dd; a3=aa; }
  }

  int anc_r[KNN];                       // winners, known to ALL lanes (static idx)
  #pragma unroll
  for (int r=0; r<KNN; r++){
    float v = d0; int anc = a0;
    if (d1 < v || (d1==v && a1<anc)){ v=d1; anc=a1; }
    if (d2 < v || (d2==v && a2<anc)){ v=d2; anc=a2; }
    if (d3 < v || (d3==v && a3<anc)){ v=d3; anc=a3; }
    #pragma unroll
    for (int off=32; off>0; off>>=1){
      float v2 = __shfl_xor(v, off);
      int  A2 = __shfl_xor(anc, off);
      if (v2 < v || (v2==v && A2<anc)){ v=v2; anc=A2; }
    }
    if (a0==anc) d0=FLT_MAX;
    if (a1==anc) d1=FLT_MAX;
    if (a2==anc) d2=FLT_MAX;
    if (a3==anc) d3=FLT_MAX;
    anc_r[r] = anc;
  }

  // scatter-match: lane j = GT j; eval this wave's 10 candidates
  bool jv = (lane < NGT);
  float4 gbj = make_float4(0.f,0.f,0.f,0.f);
  int labj = 0;
  if (jv){
    gbj  = *(const float4*)(gt + (size_t)(img*NGT + lane)*4);
    labj = labels[img*NGT + lane];
  }
  float a2g = fmaxf(gbj.z-gbj.x,0.f)*fmaxf(gbj.w-gbj.y,0.f);
  unsigned long long best = ~0ull;
  #pragma unroll
  for (int r=0; r<KNN; r++){
    int a = anc_r[r];
    ARow ar = anchor_row(p0,p1,p2,img,a);
    float4 b = decode_box_xywh(ar);     // broadcast row load (same addr all lanes)
    float bx1=b.x-b.z*0.5f, by1=b.y-b.w*0.5f, bx2=b.x+b.z*0.5f, by2=b.y+b.w*0.5f;
    float a1 = fmaxf(bx2-bx1,0.f)*fmaxf(by2-by1,0.f);
    float ix1=fmaxf(bx1,gbj.x), iy1=fmaxf(by1,gbj.y);
    float ix2=fminf(bx2,gbj.z), iy2=fminf(by2,gbj.w);
    float inter = fmaxf(ix2-ix1,0.f)*fmaxf(iy2-iy1,0.f);
    float uni = a1 + a2g - inter + EPSF;
    float iou = fminf(fmaxf(inter/uni,0.f),1.f);
    float lg = ar.q[4+labj];            // per-lane gather within the 336B row
    float cost = 0.5f*(1.f - fsigm(lg)) + 6.f*(1.f - iou);
    unsigned long long pk = ((unsigned long long)__float_as_uint(cost) << 32)
                          | ((unsigned long long)(unsigned)(g*KNN + r) << 14)
                          | (unsigned)a;
    if (pk < best) best = pk;
  }

  // block reduce across the 4 waves (4 GTs), then one write per (block, j)
  __shared__ unsigned long long red[4][64];
  red[wid][lane] = best;
  __syncthreads();
  if (wid == 0 && jv){
    unsigned long long b0 = red[0][lane], b1 = red[1][lane];
    unsigned long long b2 = red[2][lane], b3 = red[3][lane];
    unsigned long long m = b0 < b1 ? b0 : b1;
    unsigned long long n = b2 < b3 ? b2 : b3;
    partials[(size_t)blockIdx.x*NGT + lane] = m < n ? m : n;
  }
}

// K2: single block, 16 waves (one image each): min over the image's 15 block
// partials -> matched anchor; ciou + dedup'd corrections + focal reduction.
__global__ __launch_bounds__(1024) void k2_kernel(const unsigned long long* __restrict__ partials,
                                                  const float* __restrict__ gt,
                                                  const int* __restrict__ labels,
                                                  const float* __restrict__ p0,
                                                  const float* __restrict__ p1,
                                                  const float* __restrict__ p2,
                                                  const float* __restrict__ fsum,
                                                  float* __restrict__ out){
  int tid = threadIdx.x;
  int wid = tid >> 6;        // image
  int lane = tid & 63;
  __shared__ int sm[NB][NGT];
  __shared__ int sl[NB][NGT];
  __shared__ float wb[NB], wc[NB], wf[NB];
  int img = wid;
  if (lane < NGT){
    unsigned long long best = ~0ull;
    #pragma unroll
    for (int b2=0; b2<15; b2++){
      unsigned long long v = partials[(size_t)(img*15 + b2)*NGT + lane];
      if (v < best) best = v;
    }
    sm[img][lane] = (int)(best & 0x3fffull);
    sl[img][lane] = labels[img*NGT + lane];
  }
  __syncthreads();

  float local_box = 0.f, local_corr = 0.f;
  if (lane < NGT){
    int j = lane;
    int m = sm[img][j];
    ARow ar = anchor_row(p0,p1,p2,img,m);
    float4 pb = decode_box_xywh(ar);
    float px1=pb.x-pb.z*0.5f, py1=pb.y-pb.w*0.5f, px2=pb.x+pb.z*0.5f, py2=pb.y+pb.w*0.5f;
    const float* gb = gt + (size_t)(img*NGT + j)*4;
    float gx=gb[0], gy=gb[1], gz=gb[2], gw=gb[3];
    float pw=fmaxf(px2-px1,EPSF), ph=fmaxf(py2-py1,EPSF);
    float tw=fmaxf(gz-gx,EPSF),  th=fmaxf(gw-gy,EPSF);
    float inter = fmaxf(fminf(px2,gz)-fmaxf(px1,gx),0.f)*fmaxf(fminf(py2,gw)-fmaxf(py1,gy),0.f);
    float uni = pw*ph + tw*th - inter + EPSF;
    float iou = inter/uni;
    float dcx = (px1+px2)*0.5f - (gx+gz)*0.5f;
    float dcy = (py1+py2)*0.5f - (gy+gw)*0.5f;
    float cd = dcx*dcx + dcy*dcy;
    float cw = fmaxf(px2,gz) - fminf(px1,gx);
    float ch = fmaxf(py2,gw) - fminf(py1,gy);
    float c2 = cw*cw + ch*ch + EPSF;
    float dv = atanf(tw/th) - atanf(pw/ph);
    float v  = (4.f/(PIF*PIF))*dv*dv;
    float alpha = v/(v - iou + 1.f + EPSF);
    float ciou = iou - cd/c2 - alpha*v;
    local_box = 1.f - ciou;

    int lab = sl[img][j];
    bool dup = false;
    for (int j2=0; j2<j; j2++)
      if (sm[img][j2]==m && sl[img][j2]==lab){ dup=true; break; }
    if (!dup){
      float x = ar.q[4+lab];
      float s  = fsigm(x);
      float u  = fexp2(-fabsf(x)*LOG2E);
      float lt = LN2*flog2(1.0f + u);
      float sp_pos = fmaxf(-x,0.f) + lt;   // ce for tgt=1
      float sp_neg = fmaxf( x,0.f) + lt;   // ce for tgt=0
      local_corr = 0.25f*sp_pos*(1.f-s)*(1.f-s) - 0.75f*sp_neg*s*s;
    }
  }
  float local_f = fsum[tid] + fsum[tid + 1024];
  if (tid < FOCAL_BLOCKS - 2048) local_f += fsum[tid + 2048];
  #pragma unroll
  for (int off=32; off>0; off>>=1){
    local_box  += __shfl_xor(local_box,  off);
    local_corr += __shfl_xor(local_corr, off);
    local_f    += __shfl_xor(local_f,    off);
  }
  if (lane == 0){ wb[wid]=local_box; wc[wid]=local_corr; wf[wid]=local_f; }
  __syncthreads();
  if (tid == 0){
    float sb=0.f, sc=0.f, sf=0.f;
    #pragma unroll
    for (int k=0;k<NB;k++){ sb+=wb[k]; sc+=wc[k]; sf+=wf[k]; }
    out[0] = (7.5f*sb + 0.5f*(sf + sc)) / (60.f*16.f);
  }
}

extern "C" void kernel_launch(void* const* d_in, const int* in_sizes, int n_in,
                              void* d_out, int out_size, void* d_ws, size_t ws_size,
                              hipStream_t stream){
  const float* p0 = (const float*)d_in[0];
  const float* p1 = (const float*)d_in[1];
  const float* p2 = (const float*)d_in[2];
  const float* gt = (const float*)d_in[3];
  const int* labels = (const int*)d_in[4];
  float* out = (float*)d_out;

  unsigned long long* partials = (unsigned long long*)d_ws;               // 115.2 KB
  float* fsum = (float*)((char*)d_ws + (size_t)SPARSE_BLOCKS*NGT*8);      // 8.4 KB

  k1_kernel<<<K1_BLOCKS, 256, 0, stream>>>(p0, p1, p2, gt, labels, partials, fsum);
  k2_kernel<<<1, 1024, 0, stream>>>(partials, gt, labels, p0, p1, p2, fsum, out);
}

// Round 15
// 38.307 us; speedup vs baseline: 1.2412x; 1.0039x over previous
//
#include <hip/hip_runtime.h>
#include <cfloat>
#include <math.h>

#define NB   16
#define NGT  60
#define NA   8400
#define KNN  10
#define NCAND (NGT*KNN)   // 600
#define EPSF 1e-7f
#define PIF  3.14159265358979f

#define SPARSE_BLOCKS 240    // 960 (img,gt) pairs, 4 waves/block, sparse FIRST
#define FOCAL_BLOCKS  2100   // 2,688,000 / (2100*256) = exactly 5 vec4s/thread
#define K1_BLOCKS (SPARSE_BLOCKS + FOCAL_BLOCKS)

// vec4 index space over (p0,p1,p2) concatenated: 2,822,400 vec4s total.
// multiples of 21 are row starts (box channels, skipped); rest -> focal.
#define NV0   2150400u
#define NV1    537600u
#define NV2    134400u
#define FOCAL_COUNT 2688000u  // 20/21 of total

#define LOG2E 1.44269504088896341f
#define LN2   0.69314718055994531f

__device__ __forceinline__ float fexp2(float x){ return __builtin_amdgcn_exp2f(x); }
__device__ __forceinline__ float flog2(float x){ return __builtin_amdgcn_logf(x); }
__device__ __forceinline__ float frcp (float x){ return __builtin_amdgcn_rcpf(x); }

__device__ __forceinline__ float fsigm(float x){
  return frcp(1.0f + fexp2(-x*LOG2E));
}
__device__ __forceinline__ float fsoftplus(float x){
  float u = fexp2(-fabsf(x)*LOG2E);
  return fmaxf(x,0.f) + LN2*flog2(1.0f + u);
}
// fbg = softplus(x)*sigmoid(x)^2 = (x + ln(1+u)) / (1+u)^2,  u = e^-x
__device__ __forceinline__ float fbg(float x){
  float u = fexp2(fminf(-x*LOG2E, 126.0f));
  float t = frcp(1.0f + u);
  return (x + LN2*flog2(1.0f + u)) * t * t;
}

// one focal element group: remap u -> class vec4, load, 4x fbg
__device__ __forceinline__ float focal_fbg4(const float* __restrict__ p0,
                                            const float* __restrict__ p1,
                                            const float* __restrict__ p2, unsigned u){
  unsigned g = u / 20u;
  unsigned v = 21u*g + (u - 20u*g) + 1u;   // never a multiple of 21
  const float* p; unsigned vloc;
  if (v < NV0)          { p=p0; vloc = v; }
  else if (v < NV0+NV1) { p=p1; vloc = v - NV0; }
  else                  { p=p2; vloc = v - (NV0+NV1); }
  float4 x4 = *(const float4*)(p + (size_t)vloc*4u);
  return fbg(x4.x) + fbg(x4.y) + fbg(x4.z) + fbg(x4.w);
}

// row pointer + grid coords for an anchor id (decode-on-demand)
struct ARow { const float* q; float stf; int i, j; };
__device__ __forceinline__ ARow anchor_row(const float* p0,const float* p1,const float* p2,int img,int a){
  ARow r;
  if (a < 6400){ int l=a;      r.q = p0 + (size_t)(img*6400 + l)*84; r.stf= 8.f; r.i=l/80; r.j=l-80*r.i; }
  else if (a < 8000){ int l=a-6400; r.q = p1 + (size_t)(img*1600 + l)*84; r.stf=16.f; r.i=l/40; r.j=l-40*r.i; }
  else { int l=a-8000;         r.q = p2 + (size_t)(img*400  + l)*84; r.stf=32.f; r.i=l/20; r.j=l-20*r.i; }
  return r;
}
__device__ __forceinline__ float4 decode_box_xywh(const ARow& r){
  float4 x4 = *(const float4*)r.q;
  float px = (fsigm(x4.x)*2.f - 0.5f + (float)r.j)*r.stf;
  float py = (fsigm(x4.y)*2.f - 0.5f + (float)r.i)*r.stf;
  float pw = fsoftplus(x4.z)*r.stf;
  float ph = fsoftplus(x4.w)*r.stf;
  return make_float4(px,py,pw,ph);
}

// K1: blocks [0,240) = sparse path (one wave per (img,gt): exact windowed
// top-10 + scatter-match, block-reduced); blocks [240,2340) = focal stream.
// Window-prune proof: the 16 L0 anchors in the 4x4 cell block around the GT
// center have dist^2 <= 28^2+28^2 = 1568 => d10 <= 1568; any anchor outside
// the 13x13/7x7/5x5 windows has min-possible dist^2 > 1568 (strict).
// Scatter-match key: (cost_bits<<32)|(slot<<14)|anchor, slot = g*10+r = the
// reference's flattened cand index (cost>0 so float bits are monotone) ->
// u64-min == argmin with first-occurrence tie-break; anchor rides along.
// Each block min-reduces its 4 GTs' keys per j -> partials[block][j].
__global__ __launch_bounds__(256) void k1_kernel(const float* __restrict__ p0,
                                                 const float* __restrict__ p1,
                                                 const float* __restrict__ p2,
                                                 const float* __restrict__ gt,
                                                 const int* __restrict__ labels,
                                                 unsigned long long* __restrict__ partials,
                                                 float* __restrict__ fsum){
  if (blockIdx.x >= SPARSE_BLOCKS){
    // ---- focal blocks ----
    __shared__ float sbuf[4];
    const unsigned S = FOCAL_BLOCKS*256u;   // 537600
    unsigned u = (blockIdx.x - SPARSE_BLOCKS)*256u + threadIdx.x;
    float s0 = focal_fbg4(p0,p1,p2, u);
    float s1 = focal_fbg4(p0,p1,p2, u +   S);
    float s2 = focal_fbg4(p0,p1,p2, u + 2*S);
    float s3 = focal_fbg4(p0,p1,p2, u + 3*S);
    float s4 = focal_fbg4(p0,p1,p2, u + 4*S);
    float sum = (((s0 + s1) + (s2 + s3)) + s4) * 0.75f;
    #pragma unroll
    for (int off=32; off>0; off>>=1) sum += __shfl_xor(sum, off);
    int wid = threadIdx.x >> 6;
    if ((threadIdx.x & 63) == 0) sbuf[wid] = sum;
    __syncthreads();
    if (threadIdx.x == 0) fsum[blockIdx.x - SPARSE_BLOCKS] = sbuf[0]+sbuf[1]+sbuf[2]+sbuf[3];
    return;
  }

  // ---- sparse blocks: 4 waves = 4 consecutive GTs of ONE image ----
  int wid  = threadIdx.x >> 6;
  int lane = threadIdx.x & 63;
  int pair = blockIdx.x*4 + wid;        // 0..959; img constant per block (60%4==0)
  int img = pair / NGT, g = pair - img*NGT;
  const float* gb = gt + (size_t)(img*NGT + g)*4;
  float tcx = (gb[0]+gb[2])*0.5f, tcy = (gb[1]+gb[3])*0.5f;

  int jx0 = (int)(tcx * 0.125f),   iy0 = (int)(tcy * 0.125f);
  int jx1 = (int)(tcx * 0.0625f),  iy1 = (int)(tcy * 0.0625f);
  int jx2 = (int)(tcx * 0.03125f), iy2 = (int)(tcy * 0.03125f);

  float d0=FLT_MAX,d1=FLT_MAX,d2=FLT_MAX,d3=FLT_MAX;
  int   a0,a1,a2,a3;
  #pragma unroll
  for (int s=0; s<4; s++){
    int c = lane + 64*s;
    float dd = FLT_MAX; int aa = 9000000 + c;
    const float* p; int i, j, S, base, rowmul, valid = 1; float stf;
    if (c < 169)      { int r=c/13,  q=c-13*r;           i=iy0-6+r; j=jx0-6+q; S=80; base=0;    p=p0; rowmul=6400; stf= 8.f; }
    else if (c < 218) { int t=c-169; int r=t/7, q=t-7*r; i=iy1-3+r; j=jx1-3+q; S=40; base=6400; p=p1; rowmul=1600; stf=16.f; }
    else if (c < 243) { int t=c-218; int r=t/5, q=t-5*r; i=iy2-2+r; j=jx2-2+q; S=20; base=8000; p=p2; rowmul=400;  stf=32.f; }
    else { valid = 0; i=j=0; S=1; base=0; p=p0; rowmul=0; stf=0.f; }
    if (valid && i>=0 && i<S && j>=0 && j<S){
      int local = i*S + j;
      const float* q4 = p + (size_t)(img*rowmul + local)*84u;
      float2 xy = *(const float2*)q4;
      float px = (fsigm(xy.x)*2.f - 0.5f + (float)j)*stf;
      float py = (fsigm(xy.y)*2.f - 0.5f + (float)i)*stf;
      float dx=px-tcx, dy=py-tcy;
      dd = dx*dx + dy*dy;
      aa = base + local;
    }
    if (s==0){ d0=dd; a0=aa; } else if (s==1){ d1=dd; a1=aa; }
    else if (s==2){ d2=dd; a2=aa; } else { d3=dd; a3=aa; }
  }

  int anc_r[KNN];                       // winners, known to ALL lanes (static idx)
  #pragma unroll
  for (int r=0; r<KNN; r++){
    float v = d0; int anc = a0;
    if (d1 < v || (d1==v && a1<anc)){ v=d1; anc=a1; }
    if (d2 < v || (d2==v && a2<anc)){ v=d2; anc=a2; }
    if (d3 < v || (d3==v && a3<anc)){ v=d3; anc=a3; }
    #pragma unroll
    for (int off=32; off>0; off>>=1){
      float v2 = __shfl_xor(v, off);
      int  A2 = __shfl_xor(anc, off);
      if (v2 < v || (v2==v && A2<anc)){ v=v2; anc=A2; }
    }
    if (a0==anc) d0=FLT_MAX;
    if (a1==anc) d1=FLT_MAX;
    if (a2==anc) d2=FLT_MAX;
    if (a3==anc) d3=FLT_MAX;
    anc_r[r] = anc;
  }

  // scatter-match: lane j = GT j; eval this wave's 10 candidates
  bool jv = (lane < NGT);
  float4 gbj = make_float4(0.f,0.f,0.f,0.f);
  int labj = 0;
  if (jv){
    gbj  = *(const float4*)(gt + (size_t)(img*NGT + lane)*4);
    labj = labels[img*NGT + lane];
  }
  float a2g = fmaxf(gbj.z-gbj.x,0.f)*fmaxf(gbj.w-gbj.y,0.f);
  unsigned long long best = ~0ull;
  #pragma unroll
  for (int r=0; r<KNN; r++){
    int a = anc_r[r];
    ARow ar = anchor_row(p0,p1,p2,img,a);
    float4 b = decode_box_xywh(ar);     // broadcast row load (same addr all lanes)
    float bx1=b.x-b.z*0.5f, by1=b.y-b.w*0.5f, bx2=b.x+b.z*0.5f, by2=b.y+b.w*0.5f;
    float a1 = fmaxf(bx2-bx1,0.f)*fmaxf(by2-by1,0.f);
    float ix1=fmaxf(bx1,gbj.x), iy1=fmaxf(by1,gbj.y);
    float ix2=fminf(bx2,gbj.z), iy2=fminf(by2,gbj.w);
    float inter = fmaxf(ix2-ix1,0.f)*fmaxf(iy2-iy1,0.f);
    float uni = a1 + a2g - inter + EPSF;
    float iou = fminf(fmaxf(inter/uni,0.f),1.f);
    float lg = ar.q[4+labj];            // per-lane gather within the 336B row
    float cost = 0.5f*(1.f - fsigm(lg)) + 6.f*(1.f - iou);
    unsigned long long pk = ((unsigned long long)__float_as_uint(cost) << 32)
                          | ((unsigned long long)(unsigned)(g*KNN + r) << 14)
                          | (unsigned)a;
    if (pk < best) best = pk;
  }

  // block reduce across the 4 waves (4 GTs), then one write per (block, j)
  __shared__ unsigned long long red[4][64];
  red[wid][lane] = best;
  __syncthreads();
  if (wid == 0 && jv){
    unsigned long long b0 = red[0][lane], b1 = red[1][lane];
    unsigned long long b2 = red[2][lane], b3 = red[3][lane];
    unsigned long long m = b0 < b1 ? b0 : b1;
    unsigned long long n = b2 < b3 ? b2 : b3;
    partials[(size_t)blockIdx.x*NGT + lane] = m < n ? m : n;
  }
}

// K2: single block, 16 waves (one image each): min over the image's 15 block
// partials -> matched anchor; ciou + dedup'd corrections + focal reduction.
__global__ __launch_bounds__(1024) void k2_kernel(const unsigned long long* __restrict__ partials,
                                                  const float* __restrict__ gt,
                                                  const int* __restrict__ labels,
                                                  const float* __restrict__ p0,
                                                  const float* __restrict__ p1,
                                                  const float* __restrict__ p2,
                                                  const float* __restrict__ fsum,
                                                  float* __restrict__ out){
  int tid = threadIdx.x;
  int wid = tid >> 6;        // image
  int lane = tid & 63;
  __shared__ int sm[NB][NGT];
  __shared__ int sl[NB][NGT];
  __shared__ float wb[NB], wc[NB], wf[NB];
  int img = wid;
  if (lane < NGT){
    unsigned long long best = ~0ull;
    #pragma unroll
    for (int b2=0; b2<15; b2++){
      unsigned long long v = partials[(size_t)(img*15 + b2)*NGT + lane];
      if (v < best) best = v;
    }
    sm[img][lane] = (int)(best & 0x3fffull);
    sl[img][lane] = labels[img*NGT + lane];
  }
  __syncthreads();

  float local_box = 0.f, local_corr = 0.f;
  if (lane < NGT){
    int j = lane;
    int m = sm[img][j];
    ARow ar = anchor_row(p0,p1,p2,img,m);
    float4 pb = decode_box_xywh(ar);
    float px1=pb.x-pb.z*0.5f, py1=pb.y-pb.w*0.5f, px2=pb.x+pb.z*0.5f, py2=pb.y+pb.w*0.5f;
    const float* gb = gt + (size_t)(img*NGT + j)*4;
    float gx=gb[0], gy=gb[1], gz=gb[2], gw=gb[3];
    float pw=fmaxf(px2-px1,EPSF), ph=fmaxf(py2-py1,EPSF);
    float tw=fmaxf(gz-gx,EPSF),  th=fmaxf(gw-gy,EPSF);
    float inter = fmaxf(fminf(px2,gz)-fmaxf(px1,gx),0.f)*fmaxf(fminf(py2,gw)-fmaxf(py1,gy),0.f);
    float uni = pw*ph + tw*th - inter + EPSF;
    float iou = inter/uni;
    float dcx = (px1+px2)*0.5f - (gx+gz)*0.5f;
    float dcy = (py1+py2)*0.5f - (gy+gw)*0.5f;
    float cd = dcx*dcx + dcy*dcy;
    float cw = fmaxf(px2,gz) - fminf(px1,gx);
    float ch = fmaxf(py2,gw) - fminf(py1,gy);
    float c2 = cw*cw + ch*ch + EPSF;
    float dv = atanf(tw/th) - atanf(pw/ph);
    float v  = (4.f/(PIF*PIF))*dv*dv;
    float alpha = v/(v - iou + 1.f + EPSF);
    float ciou = iou - cd/c2 - alpha*v;
    local_box = 1.f - ciou;

    int lab = sl[img][j];
    bool dup = false;
    for (int j2=0; j2<j; j2++)
      if (sm[img][j2]==m && sl[img][j2]==lab){ dup=true; break; }
    if (!dup){
      float x = ar.q[4+lab];
      float s  = fsigm(x);
      float u  = fexp2(-fabsf(x)*LOG2E);
      float lt = LN2*flog2(1.0f + u);
      float sp_pos = fmaxf(-x,0.f) + lt;   // ce for tgt=1
      float sp_neg = fmaxf( x,0.f) + lt;   // ce for tgt=0
      local_corr = 0.25f*sp_pos*(1.f-s)*(1.f-s) - 0.75f*sp_neg*s*s;
    }
  }
  float local_f = fsum[tid] + fsum[tid + 1024];
  if (tid < FOCAL_BLOCKS - 2048) local_f += fsum[tid + 2048];
  #pragma unroll
  for (int off=32; off>0; off>>=1){
    local_box  += __shfl_xor(local_box,  off);
    local_corr += __shfl_xor(local_corr, off);
    local_f    += __shfl_xor(local_f,    off);
  }
  if (lane == 0){ wb[wid]=local_box; wc[wid]=local_corr; wf[wid]=local_f; }
  __syncthreads();
  if (tid == 0){
    float sb=0.f, sc=0.f, sf=0.f;
    #pragma unroll
    for (int k=0;k<NB;k++){ sb+=wb[k]; sc+=wc[k]; sf+=wf[k]; }
    out[0] = (7.5f*sb + 0.5f*(sf + sc)) / (60.f*16.f);
  }
}

extern "C" void kernel_launch(void* const* d_in, const int* in_sizes, int n_in,
                              void* d_out, int out_size, void* d_ws, size_t ws_size,
                              hipStream_t stream){
  const float* p0 = (const float*)d_in[0];
  const float* p1 = (const float*)d_in[1];
  const float* p2 = (const float*)d_in[2];
  const float* gt = (const float*)d_in[3];
  const int* labels = (const int*)d_in[4];
  float* out = (float*)d_out;

  unsigned long long* partials = (unsigned long long*)d_ws;               // 115.2 KB
  float* fsum = (float*)((char*)d_ws + (size_t)SPARSE_BLOCKS*NGT*8);      // 8.4 KB

  k1_kernel<<<K1_BLOCKS, 256, 0, stream>>>(p0, p1, p2, gt, labels, partials, fsum);
  k2_kernel<<<1, 1024, 0, stream>>>(partials, gt, labels, p0, p1, p2, fsum, out);
}